// Round 1
// baseline (456.452 us; speedup 1.0000x reference)
//
#include <hip/hip_runtime.h>

typedef long long i64;

// ---------------------------------------------------------------------------
// Edge-index dtype detection: if data is int64 (little-endian, values < 2^31),
// every odd int32 word of the first row is 0. Sampling 65536 elements makes a
// false positive on real int32 data impossible (would need 65536 zeros).
// ---------------------------------------------------------------------------
__global__ void detect64_kernel(const int* __restrict__ ei32, int E, int* __restrict__ flag) {
  __shared__ int found;
  if (threadIdx.x == 0) found = 0;
  __syncthreads();
  const int samples = 65536;
  for (int i = threadIdx.x; i < samples; i += blockDim.x) {
    i64 idx = (i64)i * E / samples;          // stays within first E int64 slots
    if (ei32[2 * idx + 1] != 0) found = 1;   // benign race
  }
  __syncthreads();
  if (threadIdx.x == 0) flag[0] = (found ? 0 : 1);  // 1 => int64 storage
}

__device__ __forceinline__ int edge_at(const int* __restrict__ ei32, int is64, i64 elem) {
  return is64 ? ei32[2 * elem] : ei32[(int)elem];
}

__global__ void count_kernel(const int* __restrict__ ei32, const int* __restrict__ flag,
                             int* __restrict__ counts, int E) {
  int e = blockIdx.x * blockDim.x + threadIdx.x;
  if (e >= E) return;
  int is64 = flag[0];
  int d = edge_at(ei32, is64, (i64)E + e);
  atomicAdd(&counts[d], 1);
}

// Single-block scan: CSR offsets, cursor copy, dinv = rsqrt(indeg + 1)
__global__ void scan_kernel(const int* __restrict__ counts, int* __restrict__ offs,
                            int* __restrict__ cursor, float* __restrict__ dinv, int N) {
  __shared__ int lsum[1024];
  int tid = threadIdx.x;
  int chunk = (N + 1023) >> 10;
  int s = tid * chunk;
  int e = min(s + chunk, N);
  int sum = 0;
  for (int i = s; i < e; ++i) sum += counts[i];
  lsum[tid] = sum;
  __syncthreads();
  for (int off = 1; off < 1024; off <<= 1) {
    int t = (tid >= off) ? lsum[tid - off] : 0;
    __syncthreads();
    lsum[tid] += t;
    __syncthreads();
  }
  int run = lsum[tid] - sum;  // exclusive prefix
  for (int i = s; i < e; ++i) {
    offs[i] = run;
    cursor[i] = run;
    dinv[i] = rsqrtf((float)counts[i] + 1.0f);
    run += counts[i];
  }
  if (tid == 1023) offs[N] = lsum[1023];
}

__global__ void fill_kernel(const int* __restrict__ ei32, const int* __restrict__ flag,
                            int* __restrict__ cursor, int* __restrict__ col, int E) {
  int e = blockIdx.x * blockDim.x + threadIdx.x;
  if (e >= E) return;
  int is64 = flag[0];
  int s = edge_at(ei32, is64, e);
  int d = edge_at(ei32, is64, (i64)E + e);
  int pos = atomicAdd(&cursor[d], 1);
  col[pos] = s;
}

// ---------------------------------------------------------------------------
// fp32 GEMM: C[N,128] = A[N,128] @ W[128,128], 128x128 tile per 256-thread
// block, 8x8 register blocking. MODE 0: C *= rowscale[r] (dinv pre-scale).
// MODE 1: C = relu(C + bias[c]) (decoder epilogue).
// xs padded to 33 floats/row: bank = (33*row + k) % 32 = (row+k)%32 -> the 4
// distinct rows a wave touches per k land in distinct banks.
// ---------------------------------------------------------------------------
template <int MODE>
__global__ __launch_bounds__(256) void gemm128_kernel(
    const float* __restrict__ A, const float* __restrict__ W,
    const float* __restrict__ scale_or_bias, float* __restrict__ C, int N) {
  __shared__ float xs[128][33];
  __shared__ float ws_[32][128];
  int row0 = blockIdx.x * 128;
  int tid = threadIdx.x;
  int tc = (tid & 15) * 8;   // 16 col-groups x 8 cols
  int tr = (tid >> 4) * 8;   // 16 row-groups x 8 rows
  float acc[8][8];
#pragma unroll
  for (int i = 0; i < 8; ++i)
#pragma unroll
    for (int j = 0; j < 8; ++j) acc[i][j] = 0.f;

  for (int kc = 0; kc < 128; kc += 32) {
#pragma unroll
    for (int t = 0; t < 4; ++t) {   // A tile: 128 rows x 32 k
      int f = tid + t * 256;
      int r = f >> 3;
      int c4 = (f & 7) << 2;
      int gr = row0 + r;
      float4 v = make_float4(0.f, 0.f, 0.f, 0.f);
      if (gr < N) v = *reinterpret_cast<const float4*>(&A[(i64)gr * 128 + kc + c4]);
      xs[r][c4 + 0] = v.x; xs[r][c4 + 1] = v.y; xs[r][c4 + 2] = v.z; xs[r][c4 + 3] = v.w;
    }
#pragma unroll
    for (int t = 0; t < 4; ++t) {   // W tile: 32 k x 128 cols
      int f = tid + t * 256;
      int k = f >> 5;
      int c4 = (f & 31) << 2;
      *reinterpret_cast<float4*>(&ws_[k][c4]) =
          *reinterpret_cast<const float4*>(&W[(i64)(kc + k) * 128 + c4]);
    }
    __syncthreads();
#pragma unroll
    for (int k = 0; k < 32; ++k) {
      float xv[8];
#pragma unroll
      for (int ri = 0; ri < 8; ++ri) xv[ri] = xs[tr + ri][k];
      float wv[8];
#pragma unroll
      for (int ci = 0; ci < 8; ++ci) wv[ci] = ws_[k][tc + ci];
#pragma unroll
      for (int ri = 0; ri < 8; ++ri)
#pragma unroll
        for (int ci = 0; ci < 8; ++ci)
          acc[ri][ci] = fmaf(xv[ri], wv[ci], acc[ri][ci]);
    }
    __syncthreads();
  }

#pragma unroll
  for (int ri = 0; ri < 8; ++ri) {
    int gr = row0 + tr + ri;
    if (gr >= N) continue;
    float mult = (MODE == 0) ? scale_or_bias[gr] : 1.f;
#pragma unroll
    for (int ci = 0; ci < 8; ci += 4) {
      float4 v;
      v.x = acc[ri][ci + 0]; v.y = acc[ri][ci + 1];
      v.z = acc[ri][ci + 2]; v.w = acc[ri][ci + 3];
      if (MODE == 0) {
        v.x *= mult; v.y *= mult; v.z *= mult; v.w *= mult;
      } else {
        v.x = fmaxf(v.x + scale_or_bias[tc + ci + 0], 0.f);
        v.y = fmaxf(v.y + scale_or_bias[tc + ci + 1], 0.f);
        v.z = fmaxf(v.z + scale_or_bias[tc + ci + 2], 0.f);
        v.w = fmaxf(v.w + scale_or_bias[tc + ci + 3], 0.f);
      }
      *reinterpret_cast<float4*>(&C[(i64)gr * 128 + tc + ci]) = v;
    }
  }
}

// ---------------------------------------------------------------------------
// Aggregation: out[v] = (relu?) ( dinv[v]*(Hp[v] + sum_{s in CSR[v]} Hp[s]) + b )
// One wave per node, lane = 2 channels (float2, 512B coalesced row reads).
// Hp is already row-prescaled by dinv, so the edge loop is pure adds.
// ---------------------------------------------------------------------------
template <int RELU>
__global__ __launch_bounds__(256) void agg_kernel(
    const float* __restrict__ Hp, const int* __restrict__ col,
    const int* __restrict__ offs, const float* __restrict__ dinv,
    const float* __restrict__ bias, float* __restrict__ out, int N) {
  int v = (int)((blockIdx.x * (i64)blockDim.x + threadIdx.x) >> 6);
  int lane = threadIdx.x & 63;
  if (v >= N) return;
  i64 base = (i64)v * 128 + lane * 2;
  float2 acc = *reinterpret_cast<const float2*>(&Hp[base]);  // self-loop term
  int beg = offs[v], end = offs[v + 1];
  int i = beg;
  for (; i + 1 < end; i += 2) {
    int s0 = col[i], s1 = col[i + 1];
    float2 a0 = *reinterpret_cast<const float2*>(&Hp[(i64)s0 * 128 + lane * 2]);
    float2 a1 = *reinterpret_cast<const float2*>(&Hp[(i64)s1 * 128 + lane * 2]);
    acc.x += a0.x + a1.x;
    acc.y += a0.y + a1.y;
  }
  if (i < end) {
    int s0 = col[i];
    float2 a0 = *reinterpret_cast<const float2*>(&Hp[(i64)s0 * 128 + lane * 2]);
    acc.x += a0.x; acc.y += a0.y;
  }
  float dv = dinv[v];
  float2 b = *reinterpret_cast<const float2*>(&bias[lane * 2]);
  float2 r;
  r.x = fmaf(acc.x, dv, b.x);
  r.y = fmaf(acc.y, dv, b.y);
  if (RELU) { r.x = fmaxf(r.x, 0.f); r.y = fmaxf(r.y, 0.f); }
  *reinterpret_cast<float2*>(&out[base]) = r;
}

// ---------------------------------------------------------------------------
extern "C" void kernel_launch(void* const* d_in, const int* in_sizes, int n_in,
                              void* d_out, int out_size, void* d_ws, size_t ws_size,
                              hipStream_t stream) {
  const float* x  = (const float*)d_in[0];
  const int*   ei = (const int*)d_in[1];
  const float* W1 = (const float*)d_in[2];
  const float* b1 = (const float*)d_in[3];
  const float* W2 = (const float*)d_in[4];
  const float* b2 = (const float*)d_in[5];
  const float* Wd = (const float*)d_in[6];
  const float* bd = (const float*)d_in[7];
  int N = in_sizes[0] / 128;
  int E = in_sizes[1] / 2;
  float* out = (float*)d_out;

  // workspace layout
  char* w = (char*)d_ws;
  float* z      = (float*)w;                               // N*128 fp32 (25.6 MB)
  int*   counts = (int*)(w + (size_t)N * 128 * sizeof(float));
  int*   offs   = counts + N;                              // N+1
  int*   cursor = offs + N + 1;                            // N
  int*   col    = cursor + N;                              // E
  float* dinv   = (float*)(col + E);                       // N
  int*   flag   = (int*)(dinv + N);                        // 1
  float* h      = out;  // d_out doubles as the H' scratch; rewritten at the end

  hipMemsetAsync(counts, 0, (size_t)N * sizeof(int), stream);
  detect64_kernel<<<1, 256, 0, stream>>>(ei, E, flag);
  count_kernel<<<(E + 255) / 256, 256, 0, stream>>>(ei, flag, counts, E);
  scan_kernel<<<1, 1024, 0, stream>>>(counts, offs, cursor, dinv, N);
  fill_kernel<<<(E + 255) / 256, 256, 0, stream>>>(ei, flag, cursor, col, E);

  int gblocks = (N + 127) / 128;
  i64 aggthreads = (i64)N * 64;
  int ablocks = (int)((aggthreads + 255) / 256);

  // conv1: H' = (x@W1)*dinv ; z = relu(dinv*(H'v + sum) + b1)
  gemm128_kernel<0><<<gblocks, 256, 0, stream>>>(x, W1, dinv, h, N);
  agg_kernel<1><<<ablocks, 256, 0, stream>>>(h, col, offs, dinv, b1, z, N);
  // conv2: H2' = (z@W2)*dinv ; z2 = dinv*(...) + b2 (no relu)
  gemm128_kernel<0><<<gblocks, 256, 0, stream>>>(z, W2, dinv, h, N);
  agg_kernel<0><<<ablocks, 256, 0, stream>>>(h, col, offs, dinv, b2, z, N);
  // decoder: out = relu(z2 @ Wd + bd)
  gemm128_kernel<1><<<gblocks, 256, 0, stream>>>(z, Wd, bd, out, N);
}

// Round 2
// 334.143 us; speedup vs baseline: 1.3660x; 1.3660x over previous
//
#include <hip/hip_runtime.h>

typedef long long i64;

// ---------------------------------------------------------------------------
// Edge-index dtype detection: if data is int64 (little-endian, values < 2^31),
// every odd int32 word of the first row is 0. Sampling 65536 elements makes a
// false positive on real int32 data impossible (would need 65536 zeros).
// ---------------------------------------------------------------------------
__global__ void detect64_kernel(const int* __restrict__ ei32, int E, int* __restrict__ flag) {
  __shared__ int found;
  if (threadIdx.x == 0) found = 0;
  __syncthreads();
  const int samples = 65536;
  for (int i = threadIdx.x; i < samples; i += blockDim.x) {
    i64 idx = (i64)i * E / samples;          // stays within first E int64 slots
    if (ei32[2 * idx + 1] != 0) found = 1;   // benign race
  }
  __syncthreads();
  if (threadIdx.x == 0) flag[0] = (found ? 0 : 1);  // 1 => int64 storage
}

__device__ __forceinline__ int edge_at(const int* __restrict__ ei32, int is64, i64 elem) {
  return is64 ? ei32[2 * elem] : ei32[(int)elem];
}

__global__ void count_kernel(const int* __restrict__ ei32, const int* __restrict__ flag,
                             int* __restrict__ counts, int E) {
  int e = blockIdx.x * blockDim.x + threadIdx.x;
  if (e >= E) return;
  int is64 = flag[0];
  int d = edge_at(ei32, is64, (i64)E + e);
  atomicAdd(&counts[d], 1);
}

// ---------------------------------------------------------------------------
// Device-wide exclusive scan of counts, 3 phases (replaces the 135us serial
// single-block scan). Each psum/scatter block covers 1024 elements.
// ---------------------------------------------------------------------------
__global__ __launch_bounds__(256) void psum_kernel(const int* __restrict__ counts,
                                                   int* __restrict__ bsum, int N) {
  int base = blockIdx.x * 1024 + threadIdx.x * 4;
  int s = 0;
#pragma unroll
  for (int j = 0; j < 4; ++j) {
    int i = base + j;
    if (i < N) s += counts[i];
  }
#pragma unroll
  for (int off = 32; off > 0; off >>= 1) s += __shfl_down(s, off);
  __shared__ int ws[4];
  int wid = threadIdx.x >> 6;
  if ((threadIdx.x & 63) == 0) ws[wid] = s;
  __syncthreads();
  if (threadIdx.x == 0) bsum[blockIdx.x] = ws[0] + ws[1] + ws[2] + ws[3];
}

// Single small block: exclusive-scan the (<=1024) block sums; also offs[N]=E.
__global__ __launch_bounds__(1024) void bscan_kernel(int* __restrict__ bsum, int nb,
                                                     int* __restrict__ offs_last, int E) {
  __shared__ int sh[1024];
  int tid = threadIdx.x;
  int v = (tid < nb) ? bsum[tid] : 0;
  sh[tid] = v;
  __syncthreads();
  for (int off = 1; off < 1024; off <<= 1) {
    int t = (tid >= off) ? sh[tid - off] : 0;
    __syncthreads();
    sh[tid] += t;
    __syncthreads();
  }
  if (tid < nb) bsum[tid] = sh[tid] - v;  // exclusive
  if (tid == 0) offs_last[0] = E;
}

__global__ __launch_bounds__(256) void scatter_kernel(
    const int* __restrict__ counts, const int* __restrict__ bsum,
    int* __restrict__ offs, int* __restrict__ cursor, float* __restrict__ dinv, int N) {
  __shared__ int wsum[4];
  int tid = threadIdx.x;
  int base = blockIdx.x * 1024 + tid * 4;
  int c[4];
  int s = 0;
#pragma unroll
  for (int j = 0; j < 4; ++j) {
    int i = base + j;
    c[j] = (i < N) ? counts[i] : 0;
    s += c[j];
  }
  int lane = tid & 63, wid = tid >> 6;
  int incl = s;
#pragma unroll
  for (int off = 1; off < 64; off <<= 1) {
    int t = __shfl_up(incl, off);
    if (lane >= off) incl += t;
  }
  if (lane == 63) wsum[wid] = incl;
  __syncthreads();
  int wo = 0;
  for (int wq = 0; wq < wid; ++wq) wo += wsum[wq];
  int excl = incl - s + wo + bsum[blockIdx.x];
#pragma unroll
  for (int j = 0; j < 4; ++j) {
    int i = base + j;
    if (i < N) {
      offs[i] = excl;
      cursor[i] = excl;
      dinv[i] = rsqrtf((float)c[j] + 1.0f);
      excl += c[j];
    }
  }
}

__global__ void fill_kernel(const int* __restrict__ ei32, const int* __restrict__ flag,
                            int* __restrict__ cursor, int* __restrict__ col, int E) {
  int e = blockIdx.x * blockDim.x + threadIdx.x;
  if (e >= E) return;
  int is64 = flag[0];
  int s = edge_at(ei32, is64, e);
  int d = edge_at(ei32, is64, (i64)E + e);
  int pos = atomicAdd(&cursor[d], 1);
  col[pos] = s;
}

// ---------------------------------------------------------------------------
// fp32 GEMM: C[N,128] = A[N,128] @ W[128,128], 128x128 tile per 256-thread
// block, 8x8 register blocking. MODE 0: C *= rowscale[r] (dinv pre-scale).
// MODE 1: C = relu(C + bias[c]) (decoder epilogue).
// ---------------------------------------------------------------------------
template <int MODE>
__global__ __launch_bounds__(256) void gemm128_kernel(
    const float* __restrict__ A, const float* __restrict__ W,
    const float* __restrict__ scale_or_bias, float* __restrict__ C, int N) {
  __shared__ float xs[128][33];
  __shared__ float ws_[32][128];
  int row0 = blockIdx.x * 128;
  int tid = threadIdx.x;
  int tc = (tid & 15) * 8;   // 16 col-groups x 8 cols
  int tr = (tid >> 4) * 8;   // 16 row-groups x 8 rows
  float acc[8][8];
#pragma unroll
  for (int i = 0; i < 8; ++i)
#pragma unroll
    for (int j = 0; j < 8; ++j) acc[i][j] = 0.f;

  for (int kc = 0; kc < 128; kc += 32) {
#pragma unroll
    for (int t = 0; t < 4; ++t) {   // A tile: 128 rows x 32 k
      int f = tid + t * 256;
      int r = f >> 3;
      int c4 = (f & 7) << 2;
      int gr = row0 + r;
      float4 v = make_float4(0.f, 0.f, 0.f, 0.f);
      if (gr < N) v = *reinterpret_cast<const float4*>(&A[(i64)gr * 128 + kc + c4]);
      xs[r][c4 + 0] = v.x; xs[r][c4 + 1] = v.y; xs[r][c4 + 2] = v.z; xs[r][c4 + 3] = v.w;
    }
#pragma unroll
    for (int t = 0; t < 4; ++t) {   // W tile: 32 k x 128 cols
      int f = tid + t * 256;
      int k = f >> 5;
      int c4 = (f & 31) << 2;
      *reinterpret_cast<float4*>(&ws_[k][c4]) =
          *reinterpret_cast<const float4*>(&W[(i64)(kc + k) * 128 + c4]);
    }
    __syncthreads();
#pragma unroll
    for (int k = 0; k < 32; ++k) {
      float xv[8];
#pragma unroll
      for (int ri = 0; ri < 8; ++ri) xv[ri] = xs[tr + ri][k];
      float wv[8];
#pragma unroll
      for (int ci = 0; ci < 8; ++ci) wv[ci] = ws_[k][tc + ci];
#pragma unroll
      for (int ri = 0; ri < 8; ++ri)
#pragma unroll
        for (int ci = 0; ci < 8; ++ci)
          acc[ri][ci] = fmaf(xv[ri], wv[ci], acc[ri][ci]);
    }
    __syncthreads();
  }

#pragma unroll
  for (int ri = 0; ri < 8; ++ri) {
    int gr = row0 + tr + ri;
    if (gr >= N) continue;
    float mult = (MODE == 0) ? scale_or_bias[gr] : 1.f;
#pragma unroll
    for (int ci = 0; ci < 8; ci += 4) {
      float4 v;
      v.x = acc[ri][ci + 0]; v.y = acc[ri][ci + 1];
      v.z = acc[ri][ci + 2]; v.w = acc[ri][ci + 3];
      if (MODE == 0) {
        v.x *= mult; v.y *= mult; v.z *= mult; v.w *= mult;
      } else {
        v.x = fmaxf(v.x + scale_or_bias[tc + ci + 0], 0.f);
        v.y = fmaxf(v.y + scale_or_bias[tc + ci + 1], 0.f);
        v.z = fmaxf(v.z + scale_or_bias[tc + ci + 2], 0.f);
        v.w = fmaxf(v.w + scale_or_bias[tc + ci + 3], 0.f);
      }
      *reinterpret_cast<float4*>(&C[(i64)gr * 128 + tc + ci]) = v;
    }
  }
}

// ---------------------------------------------------------------------------
// Aggregation: out[v] = (relu?) ( dinv[v]*(Hp[v] + sum_{s in CSR[v]} Hp[s]) + b )
// One wave per node, lane = 2 channels (float2, 512B coalesced row reads).
// Hp is already row-prescaled by dinv, so the edge loop is pure adds.
// ---------------------------------------------------------------------------
template <int RELU>
__global__ __launch_bounds__(256) void agg_kernel(
    const float* __restrict__ Hp, const int* __restrict__ col,
    const int* __restrict__ offs, const float* __restrict__ dinv,
    const float* __restrict__ bias, float* __restrict__ out, int N) {
  int v = (int)((blockIdx.x * (i64)blockDim.x + threadIdx.x) >> 6);
  int lane = threadIdx.x & 63;
  if (v >= N) return;
  i64 base = (i64)v * 128 + lane * 2;
  float2 acc = *reinterpret_cast<const float2*>(&Hp[base]);  // self-loop term
  int beg = offs[v], end = offs[v + 1];
  int i = beg;
  for (; i + 1 < end; i += 2) {
    int s0 = col[i], s1 = col[i + 1];
    float2 a0 = *reinterpret_cast<const float2*>(&Hp[(i64)s0 * 128 + lane * 2]);
    float2 a1 = *reinterpret_cast<const float2*>(&Hp[(i64)s1 * 128 + lane * 2]);
    acc.x += a0.x + a1.x;
    acc.y += a0.y + a1.y;
  }
  if (i < end) {
    int s0 = col[i];
    float2 a0 = *reinterpret_cast<const float2*>(&Hp[(i64)s0 * 128 + lane * 2]);
    acc.x += a0.x; acc.y += a0.y;
  }
  float dv = dinv[v];
  float2 b = *reinterpret_cast<const float2*>(&bias[lane * 2]);
  float2 r;
  r.x = fmaf(acc.x, dv, b.x);
  r.y = fmaf(acc.y, dv, b.y);
  if (RELU) { r.x = fmaxf(r.x, 0.f); r.y = fmaxf(r.y, 0.f); }
  *reinterpret_cast<float2*>(&out[base]) = r;
}

// ---------------------------------------------------------------------------
extern "C" void kernel_launch(void* const* d_in, const int* in_sizes, int n_in,
                              void* d_out, int out_size, void* d_ws, size_t ws_size,
                              hipStream_t stream) {
  const float* x  = (const float*)d_in[0];
  const int*   ei = (const int*)d_in[1];
  const float* W1 = (const float*)d_in[2];
  const float* b1 = (const float*)d_in[3];
  const float* W2 = (const float*)d_in[4];
  const float* b2 = (const float*)d_in[5];
  const float* Wd = (const float*)d_in[6];
  const float* bd = (const float*)d_in[7];
  int N = in_sizes[0] / 128;
  int E = in_sizes[1] / 2;
  float* out = (float*)d_out;

  // workspace layout
  char* w = (char*)d_ws;
  float* z      = (float*)w;                               // N*128 fp32 (25.6 MB)
  int*   counts = (int*)(w + (size_t)N * 128 * sizeof(float));
  int*   offs   = counts + N;                              // N+1
  int*   cursor = offs + N + 1;                            // N
  int*   col    = cursor + N;                              // E
  float* dinv   = (float*)(col + E);                       // N
  int*   flag   = (int*)(dinv + N);                        // 1
  int*   bsum   = flag + 1;                                // <=1024
  float* h      = out;  // d_out doubles as the H' scratch; rewritten at the end

  int nb = (N + 1023) / 1024;

  hipMemsetAsync(counts, 0, (size_t)N * sizeof(int), stream);
  detect64_kernel<<<1, 256, 0, stream>>>(ei, E, flag);
  count_kernel<<<(E + 255) / 256, 256, 0, stream>>>(ei, flag, counts, E);
  psum_kernel<<<nb, 256, 0, stream>>>(counts, bsum, N);
  bscan_kernel<<<1, 1024, 0, stream>>>(bsum, nb, offs + N, E);
  scatter_kernel<<<nb, 256, 0, stream>>>(counts, bsum, offs, cursor, dinv, N);
  fill_kernel<<<(E + 255) / 256, 256, 0, stream>>>(ei, flag, cursor, col, E);

  int gblocks = (N + 127) / 128;
  i64 aggthreads = (i64)N * 64;
  int ablocks = (int)((aggthreads + 255) / 256);

  // conv1: H' = (x@W1)*dinv ; z = relu(dinv*(H'v + sum) + b1)
  gemm128_kernel<0><<<gblocks, 256, 0, stream>>>(x, W1, dinv, h, N);
  agg_kernel<1><<<ablocks, 256, 0, stream>>>(h, col, offs, dinv, b1, z, N);
  // conv2: H2' = (z@W2)*dinv ; z2 = dinv*(...) + b2 (no relu)
  gemm128_kernel<0><<<gblocks, 256, 0, stream>>>(z, W2, dinv, h, N);
  agg_kernel<0><<<ablocks, 256, 0, stream>>>(h, col, offs, dinv, b2, z, N);
  // decoder: out = relu(z2 @ Wd + bd)
  gemm128_kernel<1><<<gblocks, 256, 0, stream>>>(z, Wd, bd, out, N);
}

// Round 3
// 282.453 us; speedup vs baseline: 1.6160x; 1.1830x over previous
//
#include <hip/hip_runtime.h>

typedef long long i64;

// ---------------------------------------------------------------------------
// Edge-index dtype detection: if data is int64 (little-endian, values < 2^31),
// every odd int32 word of the first row is 0. 65536 samples across 256 blocks
// (one load/thread, fully parallel). nz semantics: nz!=0 => int32 storage.
// ---------------------------------------------------------------------------
__global__ void detect64_kernel(const int* __restrict__ ei32, int E, int* __restrict__ nz) {
  int i = blockIdx.x * blockDim.x + threadIdx.x;   // 0..65535
  i64 idx = (i64)i * E / 65536;                    // within first E int64 slots
  if (ei32[2 * idx + 1] != 0) nz[0] = 1;           // benign race
}

__device__ __forceinline__ int edge_at(const int* __restrict__ ei32, int is64, i64 elem) {
  return is64 ? ei32[2 * elem] : ei32[(int)elem];
}

__global__ void count_kernel(const int* __restrict__ ei32, const int* __restrict__ nz,
                             int* __restrict__ counts, int E) {
  int e = blockIdx.x * blockDim.x + threadIdx.x;
  if (e >= E) return;
  int is64 = (nz[0] == 0);
  int d = edge_at(ei32, is64, (i64)E + e);
  atomicAdd(&counts[d], 1);
}

// ---------------------------------------------------------------------------
// Device-wide exclusive scan of counts, 3 phases. Each block covers 1024 elems.
// ---------------------------------------------------------------------------
__global__ __launch_bounds__(256) void psum_kernel(const int* __restrict__ counts,
                                                   int* __restrict__ bsum, int N) {
  int base = blockIdx.x * 1024 + threadIdx.x * 4;
  int s = 0;
#pragma unroll
  for (int j = 0; j < 4; ++j) {
    int i = base + j;
    if (i < N) s += counts[i];
  }
#pragma unroll
  for (int off = 32; off > 0; off >>= 1) s += __shfl_down(s, off);
  __shared__ int ws[4];
  int wid = threadIdx.x >> 6;
  if ((threadIdx.x & 63) == 0) ws[wid] = s;
  __syncthreads();
  if (threadIdx.x == 0) bsum[blockIdx.x] = ws[0] + ws[1] + ws[2] + ws[3];
}

// Single small block: exclusive-scan the (<=1024) block sums; also offs[N]=E.
__global__ __launch_bounds__(1024) void bscan_kernel(int* __restrict__ bsum, int nb,
                                                     int* __restrict__ offs_last, int E) {
  __shared__ int sh[1024];
  int tid = threadIdx.x;
  int v = (tid < nb) ? bsum[tid] : 0;
  sh[tid] = v;
  __syncthreads();
  for (int off = 1; off < 1024; off <<= 1) {
    int t = (tid >= off) ? sh[tid - off] : 0;
    __syncthreads();
    sh[tid] += t;
    __syncthreads();
  }
  if (tid < nb) bsum[tid] = sh[tid] - v;  // exclusive
  if (tid == 0) offs_last[0] = E;
}

__global__ __launch_bounds__(256) void scatter_kernel(
    const int* __restrict__ counts, const int* __restrict__ bsum,
    int* __restrict__ offs, int* __restrict__ cursor, float* __restrict__ dinv, int N) {
  __shared__ int wsum[4];
  int tid = threadIdx.x;
  int base = blockIdx.x * 1024 + tid * 4;
  int c[4];
  int s = 0;
#pragma unroll
  for (int j = 0; j < 4; ++j) {
    int i = base + j;
    c[j] = (i < N) ? counts[i] : 0;
    s += c[j];
  }
  int lane = tid & 63, wid = tid >> 6;
  int incl = s;
#pragma unroll
  for (int off = 1; off < 64; off <<= 1) {
    int t = __shfl_up(incl, off);
    if (lane >= off) incl += t;
  }
  if (lane == 63) wsum[wid] = incl;
  __syncthreads();
  int wo = 0;
  for (int wq = 0; wq < wid; ++wq) wo += wsum[wq];
  int excl = incl - s + wo + bsum[blockIdx.x];
#pragma unroll
  for (int j = 0; j < 4; ++j) {
    int i = base + j;
    if (i < N) {
      offs[i] = excl;
      cursor[i] = excl;
      dinv[i] = rsqrtf((float)c[j] + 1.0f);
      excl += c[j];
    }
  }
}

__global__ void fill_kernel(const int* __restrict__ ei32, const int* __restrict__ nz,
                            int* __restrict__ cursor, int* __restrict__ col, int E) {
  int e = blockIdx.x * blockDim.x + threadIdx.x;
  if (e >= E) return;
  int is64 = (nz[0] == 0);
  int s = edge_at(ei32, is64, e);
  int d = edge_at(ei32, is64, (i64)E + e);
  int pos = atomicAdd(&cursor[d], 1);
  col[pos] = s;
}

// ---------------------------------------------------------------------------
// fp32 GEMM: C[N,128] = A[N,128] @ W[128,128], 128x128 tile per 256-thread
// block, 8x8 register blocking. MODE 0: C *= rowscale[r] (dinv pre-scale).
// MODE 1: C = relu(C + bias[c]) (decoder epilogue).
// ---------------------------------------------------------------------------
template <int MODE>
__global__ __launch_bounds__(256) void gemm128_kernel(
    const float* __restrict__ A, const float* __restrict__ W,
    const float* __restrict__ scale_or_bias, float* __restrict__ C, int N) {
  __shared__ float xs[128][33];
  __shared__ float ws_[32][128];
  int row0 = blockIdx.x * 128;
  int tid = threadIdx.x;
  int tc = (tid & 15) * 8;   // 16 col-groups x 8 cols
  int tr = (tid >> 4) * 8;   // 16 row-groups x 8 rows
  float acc[8][8];
#pragma unroll
  for (int i = 0; i < 8; ++i)
#pragma unroll
    for (int j = 0; j < 8; ++j) acc[i][j] = 0.f;

  for (int kc = 0; kc < 128; kc += 32) {
#pragma unroll
    for (int t = 0; t < 4; ++t) {   // A tile: 128 rows x 32 k
      int f = tid + t * 256;
      int r = f >> 3;
      int c4 = (f & 7) << 2;
      int gr = row0 + r;
      float4 v = make_float4(0.f, 0.f, 0.f, 0.f);
      if (gr < N) v = *reinterpret_cast<const float4*>(&A[(i64)gr * 128 + kc + c4]);
      xs[r][c4 + 0] = v.x; xs[r][c4 + 1] = v.y; xs[r][c4 + 2] = v.z; xs[r][c4 + 3] = v.w;
    }
#pragma unroll
    for (int t = 0; t < 4; ++t) {   // W tile: 32 k x 128 cols
      int f = tid + t * 256;
      int k = f >> 5;
      int c4 = (f & 31) << 2;
      *reinterpret_cast<float4*>(&ws_[k][c4]) =
          *reinterpret_cast<const float4*>(&W[(i64)(kc + k) * 128 + c4]);
    }
    __syncthreads();
#pragma unroll
    for (int k = 0; k < 32; ++k) {
      float xv[8];
#pragma unroll
      for (int ri = 0; ri < 8; ++ri) xv[ri] = xs[tr + ri][k];
      float wv[8];
#pragma unroll
      for (int ci = 0; ci < 8; ++ci) wv[ci] = ws_[k][tc + ci];
#pragma unroll
      for (int ri = 0; ri < 8; ++ri)
#pragma unroll
        for (int ci = 0; ci < 8; ++ci)
          acc[ri][ci] = fmaf(xv[ri], wv[ci], acc[ri][ci]);
    }
    __syncthreads();
  }

#pragma unroll
  for (int ri = 0; ri < 8; ++ri) {
    int gr = row0 + tr + ri;
    if (gr >= N) continue;
    float mult = (MODE == 0) ? scale_or_bias[gr] : 1.f;
#pragma unroll
    for (int ci = 0; ci < 8; ci += 4) {
      float4 v;
      v.x = acc[ri][ci + 0]; v.y = acc[ri][ci + 1];
      v.z = acc[ri][ci + 2]; v.w = acc[ri][ci + 3];
      if (MODE == 0) {
        v.x *= mult; v.y *= mult; v.z *= mult; v.w *= mult;
      } else {
        v.x = fmaxf(v.x + scale_or_bias[tc + ci + 0], 0.f);
        v.y = fmaxf(v.y + scale_or_bias[tc + ci + 1], 0.f);
        v.z = fmaxf(v.z + scale_or_bias[tc + ci + 2], 0.f);
        v.w = fmaxf(v.w + scale_or_bias[tc + ci + 3], 0.f);
      }
      *reinterpret_cast<float4*>(&C[(i64)gr * 128 + tc + ci]) = v;
    }
  }
}

// ---------------------------------------------------------------------------
// Aggregation: out[v] = (relu?) ( dinv[v]*(Hp[v] + sum_{s in CSR[v]} Hp[s]) + b )
// One wave per node, lane = 2 channels (float2, 512B coalesced row reads).
// Hp is already row-prescaled by dinv, so the edge loop is pure adds.
// ---------------------------------------------------------------------------
template <int RELU>
__global__ __launch_bounds__(256) void agg_kernel(
    const float* __restrict__ Hp, const int* __restrict__ col,
    const int* __restrict__ offs, const float* __restrict__ dinv,
    const float* __restrict__ bias, float* __restrict__ out, int N) {
  int v = (int)((blockIdx.x * (i64)blockDim.x + threadIdx.x) >> 6);
  int lane = threadIdx.x & 63;
  if (v >= N) return;
  i64 base = (i64)v * 128 + lane * 2;
  float2 acc = *reinterpret_cast<const float2*>(&Hp[base]);  // self-loop term
  int beg = offs[v], end = offs[v + 1];
  int i = beg;
  for (; i + 1 < end; i += 2) {
    int s0 = col[i], s1 = col[i + 1];
    float2 a0 = *reinterpret_cast<const float2*>(&Hp[(i64)s0 * 128 + lane * 2]);
    float2 a1 = *reinterpret_cast<const float2*>(&Hp[(i64)s1 * 128 + lane * 2]);
    acc.x += a0.x + a1.x;
    acc.y += a0.y + a1.y;
  }
  if (i < end) {
    int s0 = col[i];
    float2 a0 = *reinterpret_cast<const float2*>(&Hp[(i64)s0 * 128 + lane * 2]);
    acc.x += a0.x; acc.y += a0.y;
  }
  float dv = dinv[v];
  float2 b = *reinterpret_cast<const float2*>(&bias[lane * 2]);
  float2 r;
  r.x = fmaf(acc.x, dv, b.x);
  r.y = fmaf(acc.y, dv, b.y);
  if (RELU) { r.x = fmaxf(r.x, 0.f); r.y = fmaxf(r.y, 0.f); }
  *reinterpret_cast<float2*>(&out[base]) = r;
}

// ---------------------------------------------------------------------------
extern "C" void kernel_launch(void* const* d_in, const int* in_sizes, int n_in,
                              void* d_out, int out_size, void* d_ws, size_t ws_size,
                              hipStream_t stream) {
  const float* x  = (const float*)d_in[0];
  const int*   ei = (const int*)d_in[1];
  const float* W1 = (const float*)d_in[2];
  const float* b1 = (const float*)d_in[3];
  const float* W2 = (const float*)d_in[4];
  const float* b2 = (const float*)d_in[5];
  const float* Wd = (const float*)d_in[6];
  const float* bd = (const float*)d_in[7];
  int N = in_sizes[0] / 128;
  int E = in_sizes[1] / 2;
  float* out = (float*)d_out;

  // workspace layout
  char* w = (char*)d_ws;
  float* z      = (float*)w;                               // N*128 fp32 (25.6 MB)
  int*   counts = (int*)(w + (size_t)N * 128 * sizeof(float));
  int*   offs   = counts + N;                              // N+1
  int*   cursor = offs + N + 1;                            // N
  int*   col    = cursor + N;                              // E
  float* dinv   = (float*)(col + E);                       // N
  int*   nz     = (int*)(dinv + N);                        // 1
  int*   bsum   = nz + 1;                                  // <=1024
  float* h      = out;  // d_out doubles as the H' scratch; rewritten at the end

  int nb = (N + 1023) / 1024;

  hipMemsetAsync(counts, 0, (size_t)N * sizeof(int), stream);
  hipMemsetAsync(nz, 0, sizeof(int), stream);
  detect64_kernel<<<256, 256, 0, stream>>>(ei, E, nz);
  count_kernel<<<(E + 255) / 256, 256, 0, stream>>>(ei, nz, counts, E);
  psum_kernel<<<nb, 256, 0, stream>>>(counts, bsum, N);
  bscan_kernel<<<1, 1024, 0, stream>>>(bsum, nb, offs + N, E);
  scatter_kernel<<<nb, 256, 0, stream>>>(counts, bsum, offs, cursor, dinv, N);
  fill_kernel<<<(E + 255) / 256, 256, 0, stream>>>(ei, nz, cursor, col, E);

  int gblocks = (N + 127) / 128;
  i64 aggthreads = (i64)N * 64;
  int ablocks = (int)((aggthreads + 255) / 256);

  // conv1: H' = (x@W1)*dinv ; z = relu(dinv*(H'v + sum) + b1)
  gemm128_kernel<0><<<gblocks, 256, 0, stream>>>(x, W1, dinv, h, N);
  agg_kernel<1><<<ablocks, 256, 0, stream>>>(h, col, offs, dinv, b1, z, N);
  // conv2: H2' = (z@W2)*dinv ; z2 = dinv*(...) + b2 (no relu)
  gemm128_kernel<0><<<gblocks, 256, 0, stream>>>(z, W2, dinv, h, N);
  agg_kernel<0><<<ablocks, 256, 0, stream>>>(h, col, offs, dinv, b2, z, N);
  // decoder: out = relu(z2 @ Wd + bd)
  gemm128_kernel<1><<<gblocks, 256, 0, stream>>>(z, Wd, bd, out, N);
}

// Round 4
// 219.939 us; speedup vs baseline: 2.0754x; 1.2842x over previous
//
#include <hip/hip_runtime.h>

typedef long long i64;
typedef __attribute__((ext_vector_type(8))) short short8;
typedef __attribute__((ext_vector_type(8))) unsigned short us8;
typedef __attribute__((ext_vector_type(4))) unsigned short us4;
typedef __attribute__((ext_vector_type(4))) float f32x4;

__device__ __forceinline__ unsigned short bf16_rtn(float x) {
  unsigned u = __float_as_uint(x);
  unsigned r = (u + 0x7FFFu + ((u >> 16) & 1u)) >> 16;
  return (unsigned short)r;
}
__device__ __forceinline__ float bf16_to_f(unsigned short h) {
  return __uint_as_float(((unsigned)h) << 16);
}

// ---------------------------------------------------------------------------
// Edge-index dtype detection (int64 vs int32 storage), fully parallel.
// nz != 0  =>  int32 storage.
// ---------------------------------------------------------------------------
__global__ void detect64_kernel(const int* __restrict__ ei32, int E, int* __restrict__ nz) {
  int i = blockIdx.x * blockDim.x + threadIdx.x;   // 0..65535
  i64 idx = (i64)i * E / 65536;
  if (ei32[2 * idx + 1] != 0) nz[0] = 1;           // benign race
}

__device__ __forceinline__ int edge_at(const int* __restrict__ ei32, int is64, i64 elem) {
  return is64 ? ei32[2 * elem] : ei32[(int)elem];
}

__global__ void count_kernel(const int* __restrict__ ei32, const int* __restrict__ nz,
                             int* __restrict__ counts, int E) {
  int e = blockIdx.x * blockDim.x + threadIdx.x;
  if (e >= E) return;
  int is64 = (nz[0] == 0);
  int d = edge_at(ei32, is64, (i64)E + e);
  atomicAdd(&counts[d], 1);
}

// ---------------------------------------------------------------------------
// Device-wide exclusive scan of counts (3 phases, 1024 elems per block).
// ---------------------------------------------------------------------------
__global__ __launch_bounds__(256) void psum_kernel(const int* __restrict__ counts,
                                                   int* __restrict__ bsum, int N) {
  int base = blockIdx.x * 1024 + threadIdx.x * 4;
  int s = 0;
#pragma unroll
  for (int j = 0; j < 4; ++j) {
    int i = base + j;
    if (i < N) s += counts[i];
  }
#pragma unroll
  for (int off = 32; off > 0; off >>= 1) s += __shfl_down(s, off);
  __shared__ int ws[4];
  int wid = threadIdx.x >> 6;
  if ((threadIdx.x & 63) == 0) ws[wid] = s;
  __syncthreads();
  if (threadIdx.x == 0) bsum[blockIdx.x] = ws[0] + ws[1] + ws[2] + ws[3];
}

__global__ __launch_bounds__(1024) void bscan_kernel(int* __restrict__ bsum, int nb,
                                                     int* __restrict__ offs_last, int E) {
  __shared__ int sh[1024];
  int tid = threadIdx.x;
  int v = (tid < nb) ? bsum[tid] : 0;
  sh[tid] = v;
  __syncthreads();
  for (int off = 1; off < 1024; off <<= 1) {
    int t = (tid >= off) ? sh[tid - off] : 0;
    __syncthreads();
    sh[tid] += t;
    __syncthreads();
  }
  if (tid < nb) bsum[tid] = sh[tid] - v;  // exclusive
  if (tid == 0) offs_last[0] = E;
}

__global__ __launch_bounds__(256) void scatter_kernel(
    const int* __restrict__ counts, const int* __restrict__ bsum,
    int* __restrict__ offs, int* __restrict__ cursor, float* __restrict__ dinv, int N) {
  __shared__ int wsum[4];
  int tid = threadIdx.x;
  int base = blockIdx.x * 1024 + tid * 4;
  int c[4];
  int s = 0;
#pragma unroll
  for (int j = 0; j < 4; ++j) {
    int i = base + j;
    c[j] = (i < N) ? counts[i] : 0;
    s += c[j];
  }
  int lane = tid & 63, wid = tid >> 6;
  int incl = s;
#pragma unroll
  for (int off = 1; off < 64; off <<= 1) {
    int t = __shfl_up(incl, off);
    if (lane >= off) incl += t;
  }
  if (lane == 63) wsum[wid] = incl;
  __syncthreads();
  int wo = 0;
  for (int wq = 0; wq < wid; ++wq) wo += wsum[wq];
  int excl = incl - s + wo + bsum[blockIdx.x];
#pragma unroll
  for (int j = 0; j < 4; ++j) {
    int i = base + j;
    if (i < N) {
      offs[i] = excl;
      cursor[i] = excl;
      dinv[i] = rsqrtf((float)c[j] + 1.0f);
      excl += c[j];
    }
  }
}

__global__ void fill_kernel(const int* __restrict__ ei32, const int* __restrict__ nz,
                            int* __restrict__ cursor, int* __restrict__ col, int E) {
  int e = blockIdx.x * blockDim.x + threadIdx.x;
  if (e >= E) return;
  int is64 = (nz[0] == 0);
  int s = edge_at(ei32, is64, e);
  int d = edge_at(ei32, is64, (i64)E + e);
  int pos = atomicAdd(&cursor[d], 1);
  col[pos] = s;
}

// ---------------------------------------------------------------------------
// Weight split+transpose (once per launch, per weight): W[128][128] fp32
// -> WhT[c][k], WlT[c][k] bf16, where W = hi + lo to ~2^-18 relative.
// ---------------------------------------------------------------------------
__global__ __launch_bounds__(256) void wsplit_kernel(const float* __restrict__ W,
                                                     unsigned short* __restrict__ wh,
                                                     unsigned short* __restrict__ wl) {
  int t = blockIdx.x * 256 + threadIdx.x;  // 0..16383
  int c = t >> 7, k = t & 127;
  float w = W[k * 128 + c];
  unsigned short hi = bf16_rtn(w);
  unsigned short lo = bf16_rtn(w - bf16_to_f(hi));
  wh[c * 128 + k] = hi;
  wl[c * 128 + k] = lo;
}

// ---------------------------------------------------------------------------
// Split-bf16 MFMA GEMM: C[N,128] = A[N,128] @ W[128,128] with A,W split into
// hi+lo bf16 and 3 MFMA passes (hh, lh, hl) -> ~fp32 accuracy.
// 128x128 tile per 256-thread block (4 waves), wave owns 32 rows x 128 cols
// (2x8 tiles of 16x16), mfma_f32_16x16x32_bf16, K in 4 chunks of 32.
// MODE 0: out = bf16( acc * dinv[row] )   (prescaled H' for aggregation)
// MODE 1: out = fp32 relu( acc + bias[col] )  (decoder epilogue)
// LDS pitch 40 ushorts (80 B): 16B-aligned rows, 2-way banks (free).
// ---------------------------------------------------------------------------
template <int MODE>
__global__ __launch_bounds__(256, 2) void gemm_mfma(
    const float* __restrict__ A, const unsigned short* __restrict__ WhT,
    const unsigned short* __restrict__ WlT, const float* __restrict__ aux,
    void* __restrict__ outv, int N) {
  __shared__ unsigned short ah[128][40], al[128][40];
  __shared__ unsigned short bh[128][40], bl[128][40];
  int tid = threadIdx.x;
  int row0 = blockIdx.x * 128;
  int wid = tid >> 6, lane = tid & 63;
  int lr = lane & 15, ks = (lane >> 4) * 8;

  f32x4 acc[2][8];
#pragma unroll
  for (int tr = 0; tr < 2; ++tr)
#pragma unroll
    for (int tc = 0; tc < 8; ++tc) acc[tr][tc] = (f32x4){0.f, 0.f, 0.f, 0.f};

  for (int kc = 0; kc < 128; kc += 32) {
    // stage A chunk [128 rows][32 k] fp32 -> split hi/lo bf16
#pragma unroll
    for (int t = 0; t < 4; ++t) {
      int f = tid + t * 256;
      int r = f >> 3, q = f & 7, c4 = q * 4;
      int gr = row0 + r;
      float4 v = make_float4(0.f, 0.f, 0.f, 0.f);
      if (gr < N) v = *reinterpret_cast<const float4*>(&A[(i64)gr * 128 + kc + c4]);
      float xs[4] = {v.x, v.y, v.z, v.w};
      us4 hi, lo;
#pragma unroll
      for (int j = 0; j < 4; ++j) {
        unsigned short h = bf16_rtn(xs[j]);
        hi[j] = h;
        lo[j] = bf16_rtn(xs[j] - bf16_to_f(h));
      }
      *reinterpret_cast<us4*>(&ah[r][c4]) = hi;
      *reinterpret_cast<us4*>(&al[r][c4]) = lo;
    }
    // stage B chunk [128 cols][32 k] from pre-split transposed weights
#pragma unroll
    for (int t = 0; t < 2; ++t) {
      int f = tid + t * 256;
      int c = f >> 2, k8 = (f & 3) * 8;
      *reinterpret_cast<us8*>(&bh[c][k8]) =
          *reinterpret_cast<const us8*>(&WhT[c * 128 + kc + k8]);
      *reinterpret_cast<us8*>(&bl[c][k8]) =
          *reinterpret_cast<const us8*>(&WlT[c * 128 + kc + k8]);
    }
    __syncthreads();

    short8 afh[2], afl[2];
#pragma unroll
    for (int tr = 0; tr < 2; ++tr) {
      int r = wid * 32 + tr * 16 + lr;
      afh[tr] = *reinterpret_cast<const short8*>(&ah[r][ks]);
      afl[tr] = *reinterpret_cast<const short8*>(&al[r][ks]);
    }
#pragma unroll
    for (int tc = 0; tc < 8; ++tc) {
      int c = tc * 16 + lr;
      short8 bfh = *reinterpret_cast<const short8*>(&bh[c][ks]);
      short8 bfl = *reinterpret_cast<const short8*>(&bl[c][ks]);
#pragma unroll
      for (int tr = 0; tr < 2; ++tr) {
        acc[tr][tc] = __builtin_amdgcn_mfma_f32_16x16x32_bf16(afh[tr], bfh, acc[tr][tc], 0, 0, 0);
        acc[tr][tc] = __builtin_amdgcn_mfma_f32_16x16x32_bf16(afl[tr], bfh, acc[tr][tc], 0, 0, 0);
        acc[tr][tc] = __builtin_amdgcn_mfma_f32_16x16x32_bf16(afh[tr], bfl, acc[tr][tc], 0, 0, 0);
      }
    }
    __syncthreads();
  }

  // epilogue (C/D layout: col = lane&15, row = (lane>>4)*4 + reg)
  if (MODE == 0) {
    unsigned short* hb = (unsigned short*)outv;
#pragma unroll
    for (int tr = 0; tr < 2; ++tr) {
#pragma unroll
      for (int reg = 0; reg < 4; ++reg) {
        int row = row0 + wid * 32 + tr * 16 + (lane >> 4) * 4 + reg;
        if (row >= N) continue;
        float dv = aux[row];
#pragma unroll
        for (int tc = 0; tc < 8; ++tc) {
          int colg = tc * 16 + lr;
          hb[(i64)row * 128 + colg] = bf16_rtn(acc[tr][tc][reg] * dv);
        }
      }
    }
  } else {
    float* out = (float*)outv;
#pragma unroll
    for (int tr = 0; tr < 2; ++tr) {
#pragma unroll
      for (int reg = 0; reg < 4; ++reg) {
        int row = row0 + wid * 32 + tr * 16 + (lane >> 4) * 4 + reg;
        if (row >= N) continue;
#pragma unroll
        for (int tc = 0; tc < 8; ++tc) {
          int colg = tc * 16 + lr;
          out[(i64)row * 128 + colg] = fmaxf(acc[tr][tc][reg] + aux[colg], 0.f);
        }
      }
    }
  }
}

// ---------------------------------------------------------------------------
// Aggregation over bf16 H': out[v] = (relu?)( dinv[v]*(H'[v] + sum_s H'[s]) + b )
// 2 nodes per wave: half-wave (32 lanes) per node, lane = 4 channels (8B us4).
// fp32 accumulate, fp32 output.
// ---------------------------------------------------------------------------
template <int RELU>
__global__ __launch_bounds__(256) void agg_bf16(
    const unsigned short* __restrict__ hb, const int* __restrict__ col,
    const int* __restrict__ offs, const float* __restrict__ dinv,
    const float* __restrict__ bias, float* __restrict__ out, int N) {
  i64 gt = (i64)blockIdx.x * blockDim.x + threadIdx.x;
  int gw = (int)(gt >> 6);
  int lane = threadIdx.x & 63;
  int v = gw * 2 + (lane >> 5);
  if (v >= N) return;
  int ch = (lane & 31) * 4;
  us4 sv = *reinterpret_cast<const us4*>(&hb[(i64)v * 128 + ch]);
  float a0 = bf16_to_f(sv[0]), a1 = bf16_to_f(sv[1]);
  float a2 = bf16_to_f(sv[2]), a3 = bf16_to_f(sv[3]);
  int beg = offs[v], end = offs[v + 1];
  int i = beg;
  for (; i + 1 < end; i += 2) {
    int s0 = col[i], s1 = col[i + 1];
    us4 u0 = *reinterpret_cast<const us4*>(&hb[(i64)s0 * 128 + ch]);
    us4 u1 = *reinterpret_cast<const us4*>(&hb[(i64)s1 * 128 + ch]);
    a0 += bf16_to_f(u0[0]) + bf16_to_f(u1[0]);
    a1 += bf16_to_f(u0[1]) + bf16_to_f(u1[1]);
    a2 += bf16_to_f(u0[2]) + bf16_to_f(u1[2]);
    a3 += bf16_to_f(u0[3]) + bf16_to_f(u1[3]);
  }
  if (i < end) {
    int s0 = col[i];
    us4 u0 = *reinterpret_cast<const us4*>(&hb[(i64)s0 * 128 + ch]);
    a0 += bf16_to_f(u0[0]); a1 += bf16_to_f(u0[1]);
    a2 += bf16_to_f(u0[2]); a3 += bf16_to_f(u0[3]);
  }
  float dv = dinv[v];
  float4 b = *reinterpret_cast<const float4*>(&bias[ch]);
  float4 r;
  r.x = fmaf(a0, dv, b.x);
  r.y = fmaf(a1, dv, b.y);
  r.z = fmaf(a2, dv, b.z);
  r.w = fmaf(a3, dv, b.w);
  if (RELU) {
    r.x = fmaxf(r.x, 0.f); r.y = fmaxf(r.y, 0.f);
    r.z = fmaxf(r.z, 0.f); r.w = fmaxf(r.w, 0.f);
  }
  *reinterpret_cast<float4*>(&out[(i64)v * 128 + ch]) = r;
}

// ---------------------------------------------------------------------------
extern "C" void kernel_launch(void* const* d_in, const int* in_sizes, int n_in,
                              void* d_out, int out_size, void* d_ws, size_t ws_size,
                              hipStream_t stream) {
  const float* x  = (const float*)d_in[0];
  const int*   ei = (const int*)d_in[1];
  const float* W1 = (const float*)d_in[2];
  const float* b1 = (const float*)d_in[3];
  const float* W2 = (const float*)d_in[4];
  const float* b2 = (const float*)d_in[5];
  const float* Wd = (const float*)d_in[6];
  const float* bd = (const float*)d_in[7];
  int N = in_sizes[0] / 128;
  int E = in_sizes[1] / 2;
  float* out = (float*)d_out;

  // workspace layout
  char* w = (char*)d_ws;
  float*          z    = (float*)w;                        // N*128 fp32 (reused for both conv outputs)
  unsigned short* wh1  = (unsigned short*)(z + (i64)N * 128);
  unsigned short* wl1  = wh1 + 16384;
  unsigned short* wh2  = wl1 + 16384;
  unsigned short* wl2  = wh2 + 16384;
  unsigned short* whd  = wl2 + 16384;
  unsigned short* wld  = whd + 16384;
  int*   counts = (int*)(wld + 16384);
  int*   offs   = counts + N;                              // N+1
  int*   cursor = offs + N + 1;                            // N
  int*   col    = cursor + N;                              // E
  float* dinv   = (float*)(col + E);                       // N
  int*   nz     = (int*)(dinv + N);                        // 1
  int*   bsum   = nz + 1;                                  // <=1024
  unsigned short* hb = (unsigned short*)d_out;  // bf16 H' scratch; overwritten by decoder

  int nb = (N + 1023) / 1024;

  hipMemsetAsync(counts, 0, (size_t)N * sizeof(int), stream);
  hipMemsetAsync(nz, 0, sizeof(int), stream);
  detect64_kernel<<<256, 256, 0, stream>>>(ei, E, nz);
  count_kernel<<<(E + 255) / 256, 256, 0, stream>>>(ei, nz, counts, E);
  psum_kernel<<<nb, 256, 0, stream>>>(counts, bsum, N);
  bscan_kernel<<<1, 1024, 0, stream>>>(bsum, nb, offs + N, E);
  scatter_kernel<<<nb, 256, 0, stream>>>(counts, bsum, offs, cursor, dinv, N);
  fill_kernel<<<(E + 255) / 256, 256, 0, stream>>>(ei, nz, cursor, col, E);

  wsplit_kernel<<<64, 256, 0, stream>>>(W1, wh1, wl1);
  wsplit_kernel<<<64, 256, 0, stream>>>(W2, wh2, wl2);
  wsplit_kernel<<<64, 256, 0, stream>>>(Wd, whd, wld);

  int gblocks = (N + 127) / 128;
  i64 aggthreads = (i64)((N + 1) / 2) * 64;
  int ablocks = (int)((aggthreads + 255) / 256);

  // conv1: hb = bf16((x@W1)*dinv) ; z = relu(dinv*(hb_v + sum) + b1)
  gemm_mfma<0><<<gblocks, 256, 0, stream>>>(x, wh1, wl1, dinv, hb, N);
  agg_bf16<1><<<ablocks, 256, 0, stream>>>(hb, col, offs, dinv, b1, z, N);
  // conv2: hb = bf16((z@W2)*dinv) ; z = dinv*(hb_v + sum) + b2 (no relu)
  gemm_mfma<0><<<gblocks, 256, 0, stream>>>(z, wh2, wl2, dinv, hb, N);
  agg_bf16<0><<<ablocks, 256, 0, stream>>>(hb, col, offs, dinv, b2, z, N);
  // decoder: out = relu(z @ Wd + bd)   (overwrites hb region of d_out)
  gemm_mfma<1><<<gblocks, 256, 0, stream>>>(z, whd, wld, bd, out, N);
}